// Round 4
// baseline (253.427 us; speedup 1.0000x reference)
//
#include <hip/hip_runtime.h>
#include <hip/hip_cooperative_groups.h>
#include <math.h>

namespace cg = cooperative_groups;

#define NB 8192
#define NH 4096
#define TPB 256
#define ROWS_PER_BLOCK 8
#define NBLK (NB / ROWS_PER_BLOCK)   // 1024
#define ITERS ((NH / 4) / TPB)       // 4

// ---------- fused cooperative kernel ----------
// 1024 blocks x 256 threads, 8 rows per block. Each block accumulates
// (sum_sq_err, match_count, corr_loss) over its rows, release-stores the
// triple, grid-syncs, then block 0 reduces the 1024 triples.
__global__ __launch_bounds__(TPB, 4) void fused_coop_kernel(
    const float* __restrict__ pred, const float* __restrict__ targ,
    float* __restrict__ wsf, float* __restrict__ out)
{
    const int tid  = threadIdx.x;
    const int lane = tid & 63;
    const int wave = tid >> 6;

    __shared__ float red[4][6];
    float acc_mse = 0.f, acc_M = 0.f, acc_corr = 0.f;   // live in thread 0

    for (int r = 0; r < ROWS_PER_BLOCK; ++r) {
        const int row = blockIdx.x * ROWS_PER_BLOCK + r;
        const float* p = pred + (size_t)row * NH;
        const float* t = targ + (size_t)row * NH;
        const float4* p4 = (const float4*)p;
        const float4* t4 = (const float4*)t;

        // Hoist loads: 8 outstanding float4 loads per thread.
        float4 pv[ITERS], tv[ITERS];
#pragma unroll
        for (int it = 0; it < ITERS; ++it) {
            pv[it] = p4[it * TPB + tid];
            tv[it] = t4[it * TPB + tid];
        }

        float Sp = 0.f, Spp = 0.f, St = 0.f, Stt = 0.f, Spt = 0.f;
        int M = 0;

#pragma unroll
        for (int it = 0; it < ITERS; ++it) {
            const int q = it * TPB + tid;
            const float4 P = pv[it];
            const float4 T = tv[it];

            Sp  += (P.x + P.y) + (P.z + P.w);
            St  += (T.x + T.y) + (T.z + T.w);
            Spp += (P.x * P.x + P.y * P.y) + (P.z * P.z + P.w * P.w);
            Stt += (T.x * T.x + T.y * T.y) + (T.z * T.z + T.w * T.w);
            Spt += (P.x * T.x + P.y * T.y) + (P.z * T.z + P.w * T.w);

            // prev element (4q-1): previous lane's .w; lane 0 re-loads (L1/L2 hit).
            float pprev = __shfl_up(P.w, 1);
            float tprev = __shfl_up(T.w, 1);
            if (lane == 0 && q > 0) { pprev = p[4 * q - 1]; tprev = t[4 * q - 1]; }

            if (q > 0) {
                const float dp = P.x - pprev, dt = T.x - tprev;
                M += (dt == 0.f) | (dp * dt > 0.f);
            }
            {
                const float dp1 = P.y - P.x, dt1 = T.y - T.x;
                M += (dt1 == 0.f) | (dp1 * dt1 > 0.f);
                const float dp2 = P.z - P.y, dt2 = T.z - T.y;
                M += (dt2 == 0.f) | (dp2 * dt2 > 0.f);
                const float dp3 = P.w - P.z, dt3 = T.w - T.z;
                M += (dt3 == 0.f) | (dp3 * dt3 > 0.f);
            }
        }

        float fM = (float)M;
#pragma unroll
        for (int off = 32; off > 0; off >>= 1) {
            Sp  += __shfl_down(Sp, off);
            Spp += __shfl_down(Spp, off);
            St  += __shfl_down(St, off);
            Stt += __shfl_down(Stt, off);
            Spt += __shfl_down(Spt, off);
            fM  += __shfl_down(fM, off);
        }
        if (lane == 0) {
            red[wave][0] = Sp;  red[wave][1] = Spp; red[wave][2] = St;
            red[wave][3] = Stt; red[wave][4] = Spt; red[wave][5] = fM;
        }
        __syncthreads();
        if (tid == 0) {
            Sp  = (red[0][0] + red[1][0]) + (red[2][0] + red[3][0]);
            Spp = (red[0][1] + red[1][1]) + (red[2][1] + red[3][1]);
            St  = (red[0][2] + red[1][2]) + (red[2][2] + red[3][2]);
            Stt = (red[0][3] + red[1][3]) + (red[2][3] + red[3][3]);
            Spt = (red[0][4] + red[1][4]) + (red[2][4] + red[3][4]);
            fM  = (red[0][5] + red[1][5]) + (red[2][5] + red[3][5]);

            const float invH = 1.0f / NH;
            const float mp = Sp * invH;
            const float mt = St * invH;
            const float varp = (Spp - Sp * Sp * invH) * (1.0f / (NH - 1));
            const float vart = (Stt - St * St * invH) * (1.0f / (NH - 1));
            const float sdp = sqrtf(fmaxf(varp, 0.f)) + 1e-6f;
            const float sdt = sqrtf(fmaxf(vart, 0.f)) + 1e-6f;
            const float cov = Spt * invH - mp * mt;
            const float corr = cov / (sdp * sdt);

            acc_mse  += (Spp - 2.f * Spt) + Stt;
            acc_M    += fM;                      // <= 8*4095, exact in fp32
            acc_corr += (1.f - corr) * 0.5f;
        }
        __syncthreads();   // red[] reuse next row
    }

    // Publish block triple at device scope (write-through to coherence point).
    if (tid == 0) {
        __hip_atomic_store(&wsf[3 * blockIdx.x + 0], acc_mse,  __ATOMIC_RELEASE, __HIP_MEMORY_SCOPE_AGENT);
        __hip_atomic_store(&wsf[3 * blockIdx.x + 1], acc_M,    __ATOMIC_RELEASE, __HIP_MEMORY_SCOPE_AGENT);
        __hip_atomic_store(&wsf[3 * blockIdx.x + 2], acc_corr, __ATOMIC_RELEASE, __HIP_MEMORY_SCOPE_AGENT);
    }

    cg::this_grid().sync();

    if (blockIdx.x != 0) return;

    double s_mse = 0.0, s_match = 0.0, s_corr = 0.0;
    for (int i = tid; i < NBLK; i += TPB) {   // 4 triples per thread
        s_mse   += (double)__hip_atomic_load(&wsf[3 * i + 0], __ATOMIC_RELAXED, __HIP_MEMORY_SCOPE_AGENT);
        s_match += (double)__hip_atomic_load(&wsf[3 * i + 1], __ATOMIC_RELAXED, __HIP_MEMORY_SCOPE_AGENT);
        s_corr  += (double)__hip_atomic_load(&wsf[3 * i + 2], __ATOMIC_RELAXED, __HIP_MEMORY_SCOPE_AGENT);
    }
#pragma unroll
    for (int off = 32; off > 0; off >>= 1) {
        s_mse   += __shfl_down(s_mse, off);
        s_match += __shfl_down(s_match, off);
        s_corr  += __shfl_down(s_corr, off);
    }
    __shared__ double dred[4][3];
    if (lane == 0) {
        dred[wave][0] = s_mse; dred[wave][1] = s_match; dred[wave][2] = s_corr;
    }
    __syncthreads();
    if (tid == 0) {
        s_mse   = (dred[0][0] + dred[1][0]) + (dred[2][0] + dred[3][0]);
        s_match = (dred[0][1] + dred[1][1]) + (dred[2][1] + dred[3][1]);
        s_corr  = (dred[0][2] + dred[1][2]) + (dred[2][2] + dred[3][2]);

        const double mse       = s_mse / ((double)NB * (double)NH);
        const double dir_loss  = 1.0 - s_match / ((double)NB * (double)(NH - 1));
        const double corr_loss = s_corr / (double)NB;
        out[0] = (float)(0.5 * mse + 0.25 * (dir_loss + corr_loss));
    }
}

// ---------- fallback two-kernel path (proven, 51.2 us) ----------
__global__ __launch_bounds__(TPB) void row_stats_kernel(
    const float* __restrict__ pred, const float* __restrict__ targ,
    float4* __restrict__ ws4)
{
    const int row = blockIdx.x;
    const float* p = pred + (size_t)row * NH;
    const float* t = targ + (size_t)row * NH;
    const int tid  = threadIdx.x;
    const int lane = tid & 63;
    const int wave = tid >> 6;

    const float4* p4 = (const float4*)p;
    const float4* t4 = (const float4*)t;

    float4 pv[ITERS], tv[ITERS];
#pragma unroll
    for (int it = 0; it < ITERS; ++it) {
        pv[it] = p4[it * TPB + tid];
        tv[it] = t4[it * TPB + tid];
    }

    float Sp = 0.f, Spp = 0.f, St = 0.f, Stt = 0.f, Spt = 0.f;
    int M = 0;
#pragma unroll
    for (int it = 0; it < ITERS; ++it) {
        const int q = it * TPB + tid;
        const float4 P = pv[it];
        const float4 T = tv[it];
        Sp  += (P.x + P.y) + (P.z + P.w);
        St  += (T.x + T.y) + (T.z + T.w);
        Spp += (P.x * P.x + P.y * P.y) + (P.z * P.z + P.w * P.w);
        Stt += (T.x * T.x + T.y * T.y) + (T.z * T.z + T.w * T.w);
        Spt += (P.x * T.x + P.y * T.y) + (P.z * T.z + P.w * T.w);
        float pprev = __shfl_up(P.w, 1);
        float tprev = __shfl_up(T.w, 1);
        if (lane == 0 && q > 0) { pprev = p[4 * q - 1]; tprev = t[4 * q - 1]; }
        if (q > 0) {
            const float dp = P.x - pprev, dt = T.x - tprev;
            M += (dt == 0.f) | (dp * dt > 0.f);
        }
        {
            const float dp1 = P.y - P.x, dt1 = T.y - T.x;
            M += (dt1 == 0.f) | (dp1 * dt1 > 0.f);
            const float dp2 = P.z - P.y, dt2 = T.z - T.y;
            M += (dt2 == 0.f) | (dp2 * dt2 > 0.f);
            const float dp3 = P.w - P.z, dt3 = T.w - T.z;
            M += (dt3 == 0.f) | (dp3 * dt3 > 0.f);
        }
    }

    float fM = (float)M;
#pragma unroll
    for (int off = 32; off > 0; off >>= 1) {
        Sp  += __shfl_down(Sp, off);
        Spp += __shfl_down(Spp, off);
        St  += __shfl_down(St, off);
        Stt += __shfl_down(Stt, off);
        Spt += __shfl_down(Spt, off);
        fM  += __shfl_down(fM, off);
    }
    __shared__ float red[4][6];
    if (lane == 0) {
        red[wave][0] = Sp;  red[wave][1] = Spp; red[wave][2] = St;
        red[wave][3] = Stt; red[wave][4] = Spt; red[wave][5] = fM;
    }
    __syncthreads();
    if (tid == 0) {
        Sp  = (red[0][0] + red[1][0]) + (red[2][0] + red[3][0]);
        Spp = (red[0][1] + red[1][1]) + (red[2][1] + red[3][1]);
        St  = (red[0][2] + red[1][2]) + (red[2][2] + red[3][2]);
        Stt = (red[0][3] + red[1][3]) + (red[2][3] + red[3][3]);
        Spt = (red[0][4] + red[1][4]) + (red[2][4] + red[3][4]);
        fM  = (red[0][5] + red[1][5]) + (red[2][5] + red[3][5]);
        const float invH = 1.0f / NH;
        const float mp = Sp * invH;
        const float mt = St * invH;
        const float varp = (Spp - Sp * Sp * invH) * (1.0f / (NH - 1));
        const float vart = (Stt - St * St * invH) * (1.0f / (NH - 1));
        const float sdp = sqrtf(fmaxf(varp, 0.f)) + 1e-6f;
        const float sdt = sqrtf(fmaxf(vart, 0.f)) + 1e-6f;
        const float cov = Spt * invH - mp * mt;
        const float corr = cov / (sdp * sdt);
        float4 o;
        o.x = (Spp - 2.f * Spt) + Stt;
        o.y = fM;
        o.z = (1.f - corr) * 0.5f;
        o.w = 0.f;
        ws4[row] = o;
    }
}

__global__ __launch_bounds__(TPB) void final_reduce_kernel(
    const float4* __restrict__ ws4, float* __restrict__ out)
{
    const int tid = threadIdx.x;
    double s_mse = 0.0, s_match = 0.0, s_corr = 0.0;
#pragma unroll 4
    for (int i = tid; i < NB; i += TPB) {
        const float4 v = ws4[i];
        s_mse   += (double)v.x;
        s_match += (double)v.y;
        s_corr  += (double)v.z;
    }
#pragma unroll
    for (int off = 32; off > 0; off >>= 1) {
        s_mse   += __shfl_down(s_mse, off);
        s_match += __shfl_down(s_match, off);
        s_corr  += __shfl_down(s_corr, off);
    }
    __shared__ double red[4][3];
    const int wave = tid >> 6;
    const int lane = tid & 63;
    if (lane == 0) {
        red[wave][0] = s_mse; red[wave][1] = s_match; red[wave][2] = s_corr;
    }
    __syncthreads();
    if (tid == 0) {
        s_mse   = (red[0][0] + red[1][0]) + (red[2][0] + red[3][0]);
        s_match = (red[0][1] + red[1][1]) + (red[2][1] + red[3][1]);
        s_corr  = (red[0][2] + red[1][2]) + (red[2][2] + red[3][2]);
        const double mse       = s_mse / ((double)NB * (double)NH);
        const double dir_loss  = 1.0 - s_match / ((double)NB * (double)(NH - 1));
        const double corr_loss = s_corr / (double)NB;
        out[0] = (float)(0.5 * mse + 0.25 * (dir_loss + corr_loss));
    }
}

extern "C" void kernel_launch(void* const* d_in, const int* in_sizes, int n_in,
                              void* d_out, int out_size, void* d_ws, size_t ws_size,
                              hipStream_t stream) {
    const float* pred = (const float*)d_in[0];
    const float* targ = (const float*)d_in[1];
    float* wsf = (float*)d_ws;     // coop path: 1024*3 floats = 12 KB
    float* out = (float*)d_out;

    void* args[] = {(void*)&pred, (void*)&targ, (void*)&wsf, (void*)&out};
    hipError_t err = hipLaunchCooperativeKernel(
        (const void*)fused_coop_kernel, dim3(NBLK), dim3(TPB), args, 0, stream);

    if (err != hipSuccess) {
        // Fallback: proven two-kernel path (needs 128 KB ws).
        float4* ws4 = (float4*)d_ws;
        row_stats_kernel<<<NB, TPB, 0, stream>>>(pred, targ, ws4);
        final_reduce_kernel<<<1, TPB, 0, stream>>>(ws4, out);
    }
}

// Round 5
// 49.903 us; speedup vs baseline: 5.0784x; 5.0784x over previous
//
#include <hip/hip_runtime.h>
#include <math.h>

#define NB 8192
#define NH 4096
#define TPB 256
#define ITERS ((NH / 4) / TPB)   // 4
#define RTPB 1024                // reducer threads
#define RPT (NB / RTPB)          // 8 float4s per reducer thread

// Kernel 1: one block per row. Computes Sp, Spp, St, Stt, Spt and directional
// match count M, writes 4 floats per row to ws (padded for float4 reads):
//   ws4[row] = { Spp - 2*Spt + Stt,  M,  (1-corr)/2,  0 }
__global__ __launch_bounds__(TPB) void row_stats_kernel(
    const float* __restrict__ pred, const float* __restrict__ targ,
    float4* __restrict__ ws4)
{
    const int row = blockIdx.x;
    const float* p = pred + (size_t)row * NH;
    const float* t = targ + (size_t)row * NH;
    const int tid  = threadIdx.x;
    const int lane = tid & 63;
    const int wave = tid >> 6;

    const float4* p4 = (const float4*)p;
    const float4* t4 = (const float4*)t;

    // Hoist all loads: 8 outstanding float4 loads per thread (MLP).
    float4 pv[ITERS], tv[ITERS];
#pragma unroll
    for (int it = 0; it < ITERS; ++it) {
        pv[it] = p4[it * TPB + tid];
        tv[it] = t4[it * TPB + tid];
    }

    float Sp = 0.f, Spp = 0.f, St = 0.f, Stt = 0.f, Spt = 0.f;
    int M = 0;

#pragma unroll
    for (int it = 0; it < ITERS; ++it) {
        const int q = it * TPB + tid;
        const float4 P = pv[it];
        const float4 T = tv[it];

        Sp  += (P.x + P.y) + (P.z + P.w);
        St  += (T.x + T.y) + (T.z + T.w);
        Spp += (P.x * P.x + P.y * P.y) + (P.z * P.z + P.w * P.w);
        Stt += (T.x * T.x + T.y * T.y) + (T.z * T.z + T.w * T.w);
        Spt += (P.x * T.x + P.y * T.y) + (P.z * T.z + P.w * T.w);

        // prev element (index 4q-1): previous lane's .w; lane 0 re-loads
        // (L1/L2-hit, 2 scalar loads per wave per iter).
        float pprev = __shfl_up(P.w, 1);
        float tprev = __shfl_up(T.w, 1);
        if (lane == 0 && q > 0) { pprev = p[4 * q - 1]; tprev = t[4 * q - 1]; }

        // match = (dt == 0) | (dp*dt > 0); a single flipped match moves the
        // loss by 3e-8 (threshold 2.5e-2).
        if (q > 0) {
            const float dp = P.x - pprev, dt = T.x - tprev;
            M += (dt == 0.f) | (dp * dt > 0.f);
        }
        {
            const float dp1 = P.y - P.x, dt1 = T.y - T.x;
            M += (dt1 == 0.f) | (dp1 * dt1 > 0.f);
            const float dp2 = P.z - P.y, dt2 = T.z - T.y;
            M += (dt2 == 0.f) | (dp2 * dt2 > 0.f);
            const float dp3 = P.w - P.z, dt3 = T.w - T.z;
            M += (dt3 == 0.f) | (dp3 * dt3 > 0.f);
        }
    }

    // 64-lane wave reduce.
    float fM = (float)M;   // per-thread M <= 16, wave sum <= 1024: exact fp32
#pragma unroll
    for (int off = 32; off > 0; off >>= 1) {
        Sp  += __shfl_down(Sp, off);
        Spp += __shfl_down(Spp, off);
        St  += __shfl_down(St, off);
        Stt += __shfl_down(Stt, off);
        Spt += __shfl_down(Spt, off);
        fM  += __shfl_down(fM, off);
    }

    __shared__ float red[4][6];
    if (lane == 0) {
        red[wave][0] = Sp;  red[wave][1] = Spp; red[wave][2] = St;
        red[wave][3] = Stt; red[wave][4] = Spt; red[wave][5] = fM;
    }
    __syncthreads();
    if (tid == 0) {
        Sp  = (red[0][0] + red[1][0]) + (red[2][0] + red[3][0]);
        Spp = (red[0][1] + red[1][1]) + (red[2][1] + red[3][1]);
        St  = (red[0][2] + red[1][2]) + (red[2][2] + red[3][2]);
        Stt = (red[0][3] + red[1][3]) + (red[2][3] + red[3][3]);
        Spt = (red[0][4] + red[1][4]) + (red[2][4] + red[3][4]);
        fM  = (red[0][5] + red[1][5]) + (red[2][5] + red[3][5]);

        const float invH = 1.0f / NH;
        const float mp = Sp * invH;
        const float mt = St * invH;
        const float varp = (Spp - Sp * Sp * invH) * (1.0f / (NH - 1));
        const float vart = (Stt - St * St * invH) * (1.0f / (NH - 1));
        const float sdp = sqrtf(fmaxf(varp, 0.f)) + 1e-6f;
        const float sdt = sqrtf(fmaxf(vart, 0.f)) + 1e-6f;
        const float cov = Spt * invH - mp * mt;
        const float corr = cov / (sdp * sdt);

        float4 o;
        o.x = (Spp - 2.f * Spt) + Stt;
        o.y = fM;
        o.z = (1.f - corr) * 0.5f;
        o.w = 0.f;
        ws4[row] = o;
    }
}

// Kernel 2: reduce the 8192 x float4 row results. 1024 threads; each hoists
// its 8 loads up front so the whole 128 KB arrives in one latency batch.
__global__ __launch_bounds__(RTPB) void final_reduce_kernel(
    const float4* __restrict__ ws4, float* __restrict__ out)
{
    const int tid = threadIdx.x;

    float4 v[RPT];
#pragma unroll
    for (int i = 0; i < RPT; ++i)
        v[i] = ws4[i * RTPB + tid];

    double s_mse = 0.0, s_match = 0.0, s_corr = 0.0;
#pragma unroll
    for (int i = 0; i < RPT; ++i) {
        s_mse   += (double)v[i].x;
        s_match += (double)v[i].y;
        s_corr  += (double)v[i].z;
    }
#pragma unroll
    for (int off = 32; off > 0; off >>= 1) {
        s_mse   += __shfl_down(s_mse, off);
        s_match += __shfl_down(s_match, off);
        s_corr  += __shfl_down(s_corr, off);
    }
    __shared__ double red[16][3];
    const int wave = tid >> 6;
    const int lane = tid & 63;
    if (lane == 0) {
        red[wave][0] = s_mse; red[wave][1] = s_match; red[wave][2] = s_corr;
    }
    __syncthreads();
    if (tid == 0) {
        s_mse = 0.0; s_match = 0.0; s_corr = 0.0;
#pragma unroll
        for (int w = 0; w < 16; ++w) {
            s_mse   += red[w][0];
            s_match += red[w][1];
            s_corr  += red[w][2];
        }
        const double mse       = s_mse / ((double)NB * (double)NH);
        const double dir_loss  = 1.0 - s_match / ((double)NB * (double)(NH - 1));
        const double corr_loss = s_corr / (double)NB;
        out[0] = (float)(0.5 * mse + 0.25 * (dir_loss + corr_loss));
    }
}

extern "C" void kernel_launch(void* const* d_in, const int* in_sizes, int n_in,
                              void* d_out, int out_size, void* d_ws, size_t ws_size,
                              hipStream_t stream) {
    const float* pred = (const float*)d_in[0];
    const float* targ = (const float*)d_in[1];
    float4* ws4 = (float4*)d_ws;   // 8192 * 16 B = 128 KB
    float* out  = (float*)d_out;

    row_stats_kernel<<<NB, TPB, 0, stream>>>(pred, targ, ws4);
    final_reduce_kernel<<<1, RTPB, 0, stream>>>(ws4, out);
}